// Round 11
// baseline (44.444 us; speedup 1.0000x reference)
//
#include <hip/hip_runtime.h>

typedef _Float16 half4 __attribute__((ext_vector_type(4)));
typedef _Float16 h2 __attribute__((ext_vector_type(2)));
typedef float f32x4 __attribute__((ext_vector_type(4)));

#define SINCONST 0.07957747154594767f  // 0.5 rad in revolutions

__device__ __forceinline__ unsigned int pk(float a, float b) {
    return __builtin_bit_cast(unsigned int, __builtin_amdgcn_cvt_pkrtz(a, b));
}

// factors for one patch: a = (c0c1,c0s1,s0c1,s0s1) -> 2 dwords, q = (c2c3,c2s3,s2c3,s2s3) -> 2 dwords
__device__ __forceinline__ void factors(float px0, float px1, float px2, float px3,
                                        uint2& aw, uint2& qw) {
    float t0 = px0 * SINCONST, t1 = px1 * SINCONST;
    float t2 = px2 * SINCONST, t3 = px3 * SINCONST;
    float s0 = __builtin_amdgcn_sinf(t0), c0 = __builtin_amdgcn_cosf(t0);
    float s1 = __builtin_amdgcn_sinf(t1), c1 = __builtin_amdgcn_cosf(t1);
    float s2 = __builtin_amdgcn_sinf(t2), c2 = __builtin_amdgcn_cosf(t2);
    float s3 = __builtin_amdgcn_sinf(t3), c3 = __builtin_amdgcn_cosf(t3);
    float a0 = c0 * c1, a1 = c0 * s1, a2 = s0 * c1, a3 = s0 * s1;
    float q0 = c2 * c3, q1 = c2 * s3, q2 = s2 * c3, q3 = s2 * s3;
    aw.x = pk(a0, a1); aw.y = pk(a2, a3);
    qw.x = pk(q0, q1); qw.y = pk(q2, q3);
}

// Depth-4 read pipeline: pixel pairs for j+1..j+3 live in regs, ldp(j+4) issued at iter
// top -> 3 load-pairs in flight per wave (3x the MLP of the r10 depth-2 version).
// Factors for iter j+1 -> LDS buf (j+1)&1 overlap phase2 on buf j&1 (wave-private LDS,
// same-wave DS ops in-order, no barriers).
// LDS per wave: 2 buffers x (a[128] f16x4 + q[128] u32x2) = 4 KiB.
// Phase2: 8 MFMA sub-batches; all 4 lane-groups hold identical results (Ztile rows repeat
// mod 4), so group g stores sub-batch th*4+g -> two full-wave 1 KiB coalesced nt-stores.
__global__ __launch_bounds__(256, 7) void quanv(
    const float* __restrict__ x,
    const float* __restrict__ U,
    float* __restrict__ out,
    int total, int ipw, int rem)
{
    __shared__ __align__(16) unsigned int smem[4 * 1024];  // 16 KiB -> 7 blocks/CU

    const int tid  = threadIdx.x;
    const int lane = tid & 63;
    const int wib  = tid >> 6;
    const int wave = (blockIdx.x * 256 + tid) >> 6;
    const int p16  = lane & 15;
    const int g    = lane >> 4;

    unsigned int* wbase = smem + wib * 1024;

    // A1 = U fragment: U[p16][4g+i]  (validated layout)
    half4 aU;
    {
        const float* up = U + p16 * 16 + 4 * g;
        aU[0] = (_Float16)up[0];
        aU[1] = (_Float16)up[1];
        aU[2] = (_Float16)up[2];
        aU[3] = (_Float16)up[3];
    }
    // A2 = tiled PauliZ signs: Ztile[p16][e=4g+i], wire=p16&3 (exact in f16)
    half4 aS;
    {
        int w = p16 & 3;
        #pragma unroll
        for (int i = 0; i < 4; ++i) {
            int e = 4 * g + i;
            aS[i] = ((e >> (3 - w)) & 1) ? (_Float16)-1.f : (_Float16)1.f;
        }
    }

    int cnt = ipw + (wave < rem ? 1 : 0);
    if (cnt <= 0) return;
    const int mac0 = wave * ipw + (wave < rem ? wave : rem);
    const int nPairs = total >> 1;

    // pixels for this lane's patch pair of macro-iter j (clamped, branch-free)
    auto ldp = [&](int j, float4& t4, float4& b4) {
        int PR = (mac0 + j) * 64 + lane;
        if (PR >= nPairs) PR = nPairs - 1;
        int P   = PR * 2;
        int img = P / 196;                  // compiler magic-mul
        int pp  = P - img * 196;            // even, [0,194]
        int r   = (pp * 2341) >> 15;        // pp/14
        const float4* ptr = reinterpret_cast<const float4*>(x + img * 784 + 2 * pp + 28 * r);
        t4 = ptr[0];                        // top row: patches P,P+1
        b4 = ptr[7];                        // +28 floats
    };

    // factors for macro-iter jj -> LDS buffer jj&1 (2 x ds_write_b128)
    auto do_factors = [&](int jj, float4 T, float4 Bt) {
        unsigned int* buf = wbase + (jj & 1) * 512;
        uint2 awA, qwA, awB, qwB;
        factors(T.x, T.y, Bt.x, Bt.y, awA, qwA);   // patch 2*lane
        factors(T.z, T.w, Bt.z, Bt.w, awB, qwB);   // patch 2*lane+1
        *reinterpret_cast<uint4*>(buf + lane * 4)       = make_uint4(awA.x, awA.y, awB.x, awB.y);
        *reinterpret_cast<uint4*>(buf + 256 + lane * 4) = make_uint4(qwA.x, qwA.y, qwB.x, qwB.y);
    };

    // prologue: factors(0) from a throwaway load; pipeline regs hold j+1, j+2, j+3
    {
        float4 aT, aB;
        ldp(0, aT, aB);
        do_factors(0, aT, aB);
    }
    float4 s1T, s1B, s2T, s2B, s3T, s3B;
    ldp(1, s1T, s1B);
    ldp(2, s2T, s2B);
    ldp(3, s3T, s3B);

    for (int j = 0; j < cnt; ++j) {
        // issue the deepest prefetch first (j+4)
        float4 tT, tB;
        ldp(j + 4, tT, tB);

        // factors for j+1 -> buffer (j+1)&1 (skip the garbage compute on last iter)
        if (j + 1 < cnt)
            do_factors(j + 1, s1T, s1B);

        // rotate BEFORE phase2 so only 3 pairs stay live across it
        s1T = s2T; s1B = s2B;
        s2T = s3T; s2B = s3B;
        s3T = tT;  s3B = tB;

        // ---- phase 2 on buffer j&1 (written last iteration) ----
        const unsigned int* buf2 = wbase + (j & 1) * 512;
        const unsigned short* ap = reinterpret_cast<const unsigned short*>(buf2);
        const int pbase = (mac0 + j) * 128;

        #pragma unroll
        for (int th = 0; th < 2; ++th) {
            f32x4 mm[4];
            #pragma unroll
            for (int i = 0; i < 4; ++i) {
                const int t  = th * 4 + i;
                const int pt = t * 16 + p16;
                unsigned int av = ap[pt * 4 + g];                   // ds_read_u16, imm t*128
                unsigned int dup = (av << 16) | av;                 // v_lshl_or_b32
                uint2 qw = *reinterpret_cast<const uint2*>(buf2 + 256 + pt * 2);

                h2 ag  = __builtin_bit_cast(h2, dup);
                h2 q01 = __builtin_bit_cast(h2, qw.x);
                h2 q23 = __builtin_bit_cast(h2, qw.y);
                h2 blo = ag * q01;                                  // v_pk_mul_f16
                h2 bhi = ag * q23;
                half4 bST = __builtin_shufflevector(blo, bhi, 0, 1, 2, 3);

                const f32x4 zero4 = {0.f, 0.f, 0.f, 0.f};
                f32x4 y = __builtin_amdgcn_mfma_f32_16x16x16f16(aU, bST, zero4, 0, 0, 0);

                h2 y01 = __builtin_bit_cast(h2, pk(y[0], y[1]));
                h2 y23 = __builtin_bit_cast(h2, pk(y[2], y[3]));
                h2 p01 = y01 * y01;
                h2 p23 = y23 * y23;
                half4 bP = __builtin_shufflevector(p01, p23, 0, 1, 2, 3);

                mm[i] = __builtin_amdgcn_mfma_f32_16x16x16f16(aS, bP, zero4, 0, 0, 0);
            }
            // all 4 groups hold identical mm -> group g stores sub-batch th*4+g
            f32x4 sa  = (g & 1) ? mm[1] : mm[0];
            f32x4 sb  = (g & 1) ? mm[3] : mm[2];
            f32x4 sel = (g & 2) ? sb : sa;
            int Ps = pbase + th * 64 + lane;    // = pbase + (th*4+g)*16 + p16
            if (Ps < total)
                __builtin_nontemporal_store(sel, reinterpret_cast<f32x4*>(out + (size_t)Ps * 4));
        }
    }
}

extern "C" void kernel_launch(void* const* d_in, const int* in_sizes, int n_in,
                              void* d_out, int out_size, void* d_ws, size_t ws_size,
                              hipStream_t stream) {
    const float* x = (const float*)d_in[0];
    const float* U = (const float*)d_in[1];
    float* out = (float*)d_out;

    int B = in_sizes[0] / 784;
    int total = B * 196;                  // 6,422,528 patches
    int nPairs = total / 2;               // 3,211,264 aligned pairs
    int nmac = (nPairs + 63) / 64;        // 50,176 macro-iters (128 patches each)

    // 1792 blocks = 7 blocks/CU (16 KiB LDS each = 112 KiB), 7168 waves:
    // 50176 / 7168 = 7 exactly -> rem 0, perfectly balanced, no tail.
    int nblocks = 1792;
    int nwaves = nblocks * (256 / 64);
    int ipw = nmac / nwaves;
    int rem = nmac % nwaves;

    quanv<<<nblocks, 256, 0, stream>>>(x, U, out, total, ipw, rem);
}

// Round 13
// 40.338 us; speedup vs baseline: 1.1018x; 1.1018x over previous
//
#include <hip/hip_runtime.h>

typedef _Float16 half4 __attribute__((ext_vector_type(4)));
typedef _Float16 h2 __attribute__((ext_vector_type(2)));
typedef float f32x4 __attribute__((ext_vector_type(4)));

#define SINCONST 0.07957747154594767f  // 0.5 rad in revolutions

// zero-instruction compiler memory fence: forbids reordering LDS ops across
// phase boundaries (HW DS is in-order; this pins the compiler to program order)
#define CFENCE() asm volatile("" ::: "memory")

__device__ __forceinline__ unsigned int pk(float a, float b) {
    return __builtin_bit_cast(unsigned int, __builtin_amdgcn_cvt_pkrtz(a, b));
}

__device__ __forceinline__ float uf(unsigned int u) {
    return __builtin_bit_cast(float, u);
}

// factors for one patch: a = f16x4 (c0c1,c0s1,s0c1,s0s1), q = f16x4 (c2c3,c2s3,s2c3,s2s3)
__device__ __forceinline__ void factors(float px0, float px1, float px2, float px3,
                                        uint2& aw, uint2& qw) {
    float t0 = px0 * SINCONST, t1 = px1 * SINCONST;
    float t2 = px2 * SINCONST, t3 = px3 * SINCONST;
    float s0 = __builtin_amdgcn_sinf(t0), c0 = __builtin_amdgcn_cosf(t0);
    float s1 = __builtin_amdgcn_sinf(t1), c1 = __builtin_amdgcn_cosf(t1);
    float s2 = __builtin_amdgcn_sinf(t2), c2 = __builtin_amdgcn_cosf(t2);
    float s3 = __builtin_amdgcn_sinf(t3), c3 = __builtin_amdgcn_cosf(t3);
    float a0 = c0 * c1, a1 = c0 * s1, a2 = s0 * c1, a3 = s0 * s1;
    float q0 = c2 * c3, q1 = c2 * s3, q2 = s2 * c3, q3 = s2 * s3;
    aw.x = pk(a0, a1); aw.y = pk(a2, a3);
    qw.x = pk(q0, q1); qw.y = pk(q2, q3);
}

// Chunk-streamed: chunk = 112 consecutive float4s of x (1792 B, fully dense cache
// lines) = 8 global row-pairs = 112 patches contiguous in canonical output order.
// Per wave-iter: (1) issue dense loads for chunk j+1; (2) factors from raw LDS
// (written last iter), f16 factors -> LDS; (3) 7 MFMA batches + 2 coalesced stores;
// (4) dump chunk j+1 regs -> raw LDS. Wave-private LDS slice (896 dw):
//   raw u32 [0,448) | a f16x4 [448,672) | q f16x4 [672,896).
// ALL raw-area accesses use unsigned-int vector types (single TBAA family) and
// phases are separated by CFENCE() -- r12's failure was compiler reordering of
// the float4-write/float2-read raw path (TBAA no-alias), not geometry.
__global__ __launch_bounds__(256) void quanv(
    const float* __restrict__ x,
    const float* __restrict__ U,
    float* __restrict__ out,
    int nchunks)
{
    __shared__ __align__(16) unsigned int smem[4 * 896];  // 14336 B -> 8 blocks/CU

    const int tid  = threadIdx.x;
    const int lane = tid & 63;
    const int wib  = tid >> 6;
    const int wave = (blockIdx.x * 256 + tid) >> 6;
    const int p16  = lane & 15;
    const int g    = lane >> 4;

    unsigned int* wl = smem + wib * 896;

    // A1 = U fragment: U[p16][4g+i]  (validated layout)
    half4 aU;
    {
        const float* up = U + p16 * 16 + 4 * g;
        aU[0] = (_Float16)up[0];
        aU[1] = (_Float16)up[1];
        aU[2] = (_Float16)up[2];
        aU[3] = (_Float16)up[3];
    }
    // A2 = tiled PauliZ signs: Ztile[p16][e=4g+i], wire=p16&3 (exact in f16)
    half4 aS;
    {
        int w = p16 & 3;
        #pragma unroll
        for (int i = 0; i < 4; ++i) {
            int e = 4 * g + i;
            aS[i] = ((e >> (3 - w)) & 1) ? (_Float16)-1.f : (_Float16)1.f;
        }
    }

    const int ch0 = wave * 7;                      // 7 chunks/wave (exact for B=32768)
    int cnt = nchunks - ch0;
    if (cnt <= 0) return;
    if (cnt > 7) cnt = 7;

    const uint4* xu = reinterpret_cast<const uint4*>(x);

    // prologue: dense-load chunk ch0, dump raw to LDS
    uint4 v0, v1;
    {
        const uint4* src = xu + (size_t)ch0 * 112;
        v0 = src[lane];
        if (lane < 48) v1 = src[64 + lane];
    }
    *reinterpret_cast<uint4*>(wl + 4 * lane) = v0;
    if (lane < 48) *reinterpret_cast<uint4*>(wl + 256 + 4 * lane) = v1;
    CFENCE();

    for (int j = 0; j < cnt; ++j) {
        const int ch = ch0 + j;

        // 1. issue dense loads for chunk j+1 (consumed at step 4)
        if (j + 1 < cnt) {
            const uint4* src = xu + (size_t)(ch + 1) * 112;
            v0 = src[lane];
            if (lane < 48) v1 = src[64 + lane];
        }

        // 2. factors for own patches (p = lane, and p = 64+lane for lane < 48)
        {
            const int p = lane;
            int rp = (p * 2341) >> 15;          // p/14, exact for p<=227
            int base = 2 * p + 28 * rp;         // = 56*rp + 2*c (dwords)
            uint2 t2 = *reinterpret_cast<const uint2*>(wl + base);
            uint2 b2 = *reinterpret_cast<const uint2*>(wl + base + 28);
            uint2 aw, qw;
            factors(uf(t2.x), uf(t2.y), uf(b2.x), uf(b2.y), aw, qw);
            *reinterpret_cast<uint2*>(wl + 448 + 2 * p) = aw;
            *reinterpret_cast<uint2*>(wl + 672 + 2 * p) = qw;
        }
        if (lane < 48) {
            const int p = 64 + lane;
            int rp = (p * 2341) >> 15;
            int base = 2 * p + 28 * rp;
            uint2 t2 = *reinterpret_cast<const uint2*>(wl + base);
            uint2 b2 = *reinterpret_cast<const uint2*>(wl + base + 28);
            uint2 aw, qw;
            factors(uf(t2.x), uf(t2.y), uf(b2.x), uf(b2.y), aw, qw);
            *reinterpret_cast<uint2*>(wl + 448 + 2 * p) = aw;
            *reinterpret_cast<uint2*>(wl + 672 + 2 * p) = qw;
        }
        CFENCE();

        // 3. MFMA phase: 7 batches of 16 patches
        const unsigned short* ap = reinterpret_cast<const unsigned short*>(wl + 448);
        const int pbase = ch * 112;
        f32x4* out4 = reinterpret_cast<f32x4*>(out);

        auto batch = [&](int t) -> f32x4 {
            const int pt = t * 16 + p16;
            unsigned int av = ap[pt * 4 + g];                       // a[pt][g]
            unsigned int dup = (av << 16) | av;
            uint2 qw = *reinterpret_cast<const uint2*>(wl + 672 + 2 * pt);

            h2 ag  = __builtin_bit_cast(h2, dup);
            h2 q01 = __builtin_bit_cast(h2, qw.x);
            h2 q23 = __builtin_bit_cast(h2, qw.y);
            h2 blo = ag * q01;
            h2 bhi = ag * q23;
            half4 bST = __builtin_shufflevector(blo, bhi, 0, 1, 2, 3);

            const f32x4 zero4 = {0.f, 0.f, 0.f, 0.f};
            f32x4 y = __builtin_amdgcn_mfma_f32_16x16x16f16(aU, bST, zero4, 0, 0, 0);

            h2 y01 = __builtin_bit_cast(h2, pk(y[0], y[1]));
            h2 y23 = __builtin_bit_cast(h2, pk(y[2], y[3]));
            h2 p01 = y01 * y01;
            h2 p23 = y23 * y23;
            half4 bP = __builtin_shufflevector(p01, p23, 0, 1, 2, 3);

            return __builtin_amdgcn_mfma_f32_16x16x16f16(aS, bP, zero4, 0, 0, 0);
        };

        {   // cluster A: batches 0..3 -> group g stores batch g (patches pbase+[0,64))
            f32x4 m0 = batch(0), m1 = batch(1), m2 = batch(2), m3 = batch(3);
            f32x4 sa  = (g & 1) ? m1 : m0;
            f32x4 sb  = (g & 1) ? m3 : m2;
            f32x4 sel = (g & 2) ? sb : sa;
            __builtin_nontemporal_store(sel, out4 + pbase + lane);
        }
        {   // cluster B: batches 4..6 -> groups 0..2 store (patches pbase+[64,112))
            f32x4 m0 = batch(4), m1 = batch(5), m2 = batch(6);
            f32x4 sel = (g & 1) ? m1 : m0;
            sel = (g & 2) ? m2 : sel;
            if (lane < 48)
                __builtin_nontemporal_store(sel, out4 + pbase + 64 + lane);
        }
        CFENCE();

        // 4. dump chunk j+1 into raw LDS (fenced both sides)
        if (j + 1 < cnt) {
            *reinterpret_cast<uint4*>(wl + 4 * lane) = v0;
            if (lane < 48) *reinterpret_cast<uint4*>(wl + 256 + 4 * lane) = v1;
        }
        CFENCE();
    }
}

extern "C" void kernel_launch(void* const* d_in, const int* in_sizes, int n_in,
                              void* d_out, int out_size, void* d_ws, size_t ws_size,
                              hipStream_t stream) {
    const float* x = (const float*)d_in[0];
    const float* U = (const float*)d_in[1];
    float* out = (float*)d_out;

    int B = in_sizes[0] / 784;
    int nchunks = (B * 784) / 448;        // 57,344 for B=32768 (B%4==0 assumed)
    int nwaves = (nchunks + 6) / 7;       // 8192
    int nblocks = (nwaves + 3) / 4;       // 2048

    quanv<<<nblocks, 256, 0, stream>>>(x, U, out, nchunks);
}